// Round 4
// baseline (238.982 us; speedup 1.0000x reference)
//
#include <hip/hip_runtime.h>
#include <math.h>

// Causal depthwise conv1d K=4 + SiLU. x (B=4, T=4096, C=2048) fp32, kernel (4, C) fp32.
// y[b,t,c] = silu( sum_j k[j,c] * x[b,t-j,c] ), zero-padded; next_cache = x[:, T-3:, :].
//
// R5 post-mortem: oversubscribed grid + tiny body broke the 81us wall (dwconv ~72us,
//   fell out of top-5). Still ~3 TB/s vs 6.6 achievable in-session -> not roofline.
// R6: (a) TG=8 rows/thread: 15 loads (4 kern L1-hot first, 3 halo, 8 body), 8 stores.
//   ~11KB in flight per wave; VGPR demand ~95 forces the load cluster to stay live.
//   Load amplification 1.75x -> 1.375x. Grid 4096 = 16 blocks/CU backfill.
//   (b) XCD-aware bijective block swizzle (4096%8==0): blocks sharing halo rows now
//   land on the same XCD's L2 -> halo re-reads are L2 hits instead of LLC/HBM.

#define B_   4
#define T_   4096
#define C_   2048
#define K_   4
#define C4_  (C_ / 4)   // 512 float4 groups per row
#define TG_  8          // t rows per thread
#define NT_  (T_ / TG_) // 512 t-groups
#define NXCD_ 8

__device__ __forceinline__ float silu_f(float v) {
    return v * __builtin_amdgcn_rcpf(1.f + __expf(-v));
}

__global__ __launch_bounds__(256, 4) void dwconv_silu_kernel(
    const float4* __restrict__ x,      // [B, T, C4]
    const float4* __restrict__ kern,   // [K, C4]
    float4* __restrict__ y,            // [B, T, C4]
    float4* __restrict__ cache)        // [B, K-1, C4]
{
    // XCD swizzle: consecutive work-chunks pin to one XCD's L2 so halo rows are
    // re-read from the same L2 that just fetched them as body rows.
    const int nwg   = (B_ * NT_ * C4_) / 256;          // 4096
    const int chunk = nwg / NXCD_;                     // 512
    const int wg    = (blockIdx.x % NXCD_) * chunk + blockIdx.x / NXCD_;

    // Linear thread id over (b, tg, c4): lanes span consecutive c4 -> every
    // load/store is a contiguous 1 KB wave transaction.
    const int j  = wg * 256 + threadIdx.x;
    const int c4 = j & (C4_ - 1);
    const int tg = (j >> 9) & (NT_ - 1);
    const int b  = j >> 18;            // 9 bits c4 + 9 bits tg
    const int t0 = tg * TG_;

    const float4* xp = x + (((size_t)b * T_ + t0) * C4_ + c4);

    // kern first: L1/L2-hot, oldest in the vmcnt queue -> x-waits stay graduated.
    const float4 k0 = kern[0 * C4_ + c4];
    const float4 k1 = kern[1 * C4_ + c4];
    const float4 k2 = kern[2 * C4_ + c4];
    const float4 k3 = kern[3 * C4_ + c4];

    // Halo rows x[t0-3..t0-1]; tg is block-uniform so no divergence.
    float4 m3, m2, m1;
    if (t0 == 0) {
        m3 = m2 = m1 = make_float4(0.f, 0.f, 0.f, 0.f);
    } else {
        m3 = xp[-3 * C4_];
        m2 = xp[-2 * C4_];
        m1 = xp[-1 * C4_];
    }
    // Body rows x[t0..t0+7] — 8 independent loads, ~8 KB/wave in flight.
    const float4 a0 = xp[0 * C4_];
    const float4 a1 = xp[1 * C4_];
    const float4 a2 = xp[2 * C4_];
    const float4 a3 = xp[3 * C4_];
    const float4 a4 = xp[4 * C4_];
    const float4 a5 = xp[5 * C4_];
    const float4 a6 = xp[6 * C4_];
    const float4 a7 = xp[7 * C4_];

    // Keep the load cluster above the compute cluster.
    __builtin_amdgcn_sched_barrier(0);

#define CONV1(r, a, w1, w2, w3)                                              \
    r.x = fmaf(k0.x, a.x, fmaf(k1.x, w1.x, fmaf(k2.x, w2.x, k3.x * w3.x)));  \
    r.y = fmaf(k0.y, a.y, fmaf(k1.y, w1.y, fmaf(k2.y, w2.y, k3.y * w3.y)));  \
    r.z = fmaf(k0.z, a.z, fmaf(k1.z, w1.z, fmaf(k2.z, w2.z, k3.z * w3.z)));  \
    r.w = fmaf(k0.w, a.w, fmaf(k1.w, w1.w, fmaf(k2.w, w2.w, k3.w * w3.w)));  \
    r.x = silu_f(r.x); r.y = silu_f(r.y); r.z = silu_f(r.z); r.w = silu_f(r.w);

    float4* yp = y + (((size_t)b * T_ + t0) * C4_ + c4);
    float4 r;
    CONV1(r, a0, m1, m2, m3)  yp[0 * C4_] = r;
    CONV1(r, a1, a0, m1, m2)  yp[1 * C4_] = r;
    CONV1(r, a2, a1, a0, m1)  yp[2 * C4_] = r;
    CONV1(r, a3, a2, a1, a0)  yp[3 * C4_] = r;
    CONV1(r, a4, a3, a2, a1)  yp[4 * C4_] = r;
    CONV1(r, a5, a4, a3, a2)  yp[5 * C4_] = r;
    CONV1(r, a6, a5, a4, a3)  yp[6 * C4_] = r;
    CONV1(r, a7, a6, a5, a4)  yp[7 * C4_] = r;
#undef CONV1

    // Fused next_cache = x[:, T-3:, :]: the last t-group (t0 = T-8) already holds
    // a5 = x[T-3], a6 = x[T-2], a7 = x[T-1].
    if (tg == NT_ - 1) {
        float4* cb = cache + (size_t)b * (K_ - 1) * C4_ + c4;
        cb[0 * C4_] = a5;
        cb[1 * C4_] = a6;
        cb[2 * C4_] = a7;
    }
}

extern "C" void kernel_launch(void* const* d_in, const int* in_sizes, int n_in,
                              void* d_out, int out_size, void* d_ws, size_t ws_size,
                              hipStream_t stream)
{
    const float4* x    = (const float4*)d_in[0];
    const float4* kern = (const float4*)d_in[1];
    float*        out  = (float*)d_out;

    float4* y     = (float4*)out;
    float4* cache = (float4*)(out + (size_t)B_ * T_ * C_);

    const int total_threads = B_ * NT_ * C4_;          // 1,048,576
    dim3 grid(total_threads / 256);                    // 4096 blocks
    dim3 block(256);
    dwconv_silu_kernel<<<grid, block, 0, stream>>>(x, kern, y, cache);
}

// Round 5
// 230.391 us; speedup vs baseline: 1.0373x; 1.0373x over previous
//
#include <hip/hip_runtime.h>
#include <math.h>

// Causal depthwise conv1d K=4 + SiLU. x (B=4, T=4096, C=2048) fp32, kernel (4, C) fp32.
// y[b,t,c] = silu( sum_j k[j,c] * x[b,t-j,c] ), zero-padded; next_cache = x[:, T-3:, :].
//
// R6 post-mortem: TG=8 + swizzle regressed to the 82-84us wall with VGPR=36 -- the
//   pressure-minimizing scheduler sank/serialized the load batch AGAIN despite
//   sched_barrier(0). Four rounds of VGPR={36,36,56,36} prove hints don't work.
// R7: exact R5 shape (TG=4, 8192 blocks, 256 thr -- the only config that beat the
//   wall, ~72us) + LIVENESS BALLAST: an empty asm volatile consuming every loaded
//   value. This is a data dependence, not a hint: all 11 loads must issue before
//   the asm and their destinations must coexist -> guaranteed 7KB/wave in flight.
//   Attribution check: VGPR must jump to ~72-96. If it does and dur stays ~72us,
//   per-wave MLP is non-binding -> the wall is the mixed R/W stream (probe stores next).

#define B_   4
#define T_   4096
#define C_   2048
#define K_   4
#define C4_  (C_ / 4)   // 512 float4 groups per row
#define TG_  4          // t rows per thread
#define NT_  (T_ / TG_) // 1024 t-groups

typedef float f4 __attribute__((ext_vector_type(4)));

__device__ __forceinline__ float silu_f(float v) {
    return v * __builtin_amdgcn_rcpf(1.f + __expf(-v));
}

__global__ __launch_bounds__(256, 4) void dwconv_silu_kernel(
    const f4* __restrict__ x,      // [B, T, C4]
    const f4* __restrict__ kern,   // [K, C4]
    f4* __restrict__ y,            // [B, T, C4]
    f4* __restrict__ cache)        // [B, K-1, C4]
{
    // Linear thread id over (b, tg, c4): lanes span consecutive c4 -> every
    // load/store is a contiguous 1 KB wave transaction.
    const int j  = blockIdx.x * 256 + threadIdx.x;
    const int c4 = j & (C4_ - 1);
    const int tg = (j >> 9) & (NT_ - 1);
    const int b  = j >> 19;            // 9 bits c4 + 10 bits tg
    const int t0 = tg * TG_;

    const f4* xp = x + (((size_t)b * T_ + t0) * C4_ + c4);

    // kern first: L1/L2-hot, oldest in the vmcnt queue.
    f4 k0 = kern[0 * C4_ + c4];
    f4 k1 = kern[1 * C4_ + c4];
    f4 k2 = kern[2 * C4_ + c4];
    f4 k3 = kern[3 * C4_ + c4];

    // Halo rows x[t0-3..t0-1]; tg is block-uniform so no divergence.
    f4 m3, m2, m1;
    if (t0 == 0) {
        m3 = m2 = m1 = (f4){0.f, 0.f, 0.f, 0.f};
    } else {
        m3 = xp[-3 * C4_];
        m2 = xp[-2 * C4_];
        m1 = xp[-1 * C4_];
    }
    // Body rows x[t0..t0+3].
    f4 a0 = xp[0 * C4_];
    f4 a1 = xp[1 * C4_];
    f4 a2 = xp[2 * C4_];
    f4 a3 = xp[3 * C4_];

    // LIVENESS BALLAST: every loaded value is an input to this empty asm.
    // The scheduler cannot sink any load past it, and the allocator must keep
    // all 11 results (44 VGPRs) live simultaneously -> loads overlap in flight.
    asm volatile(""
        :
        : "v"(k0), "v"(k1), "v"(k2), "v"(k3),
          "v"(m3), "v"(m2), "v"(m1),
          "v"(a0), "v"(a1), "v"(a2), "v"(a3));

#define CONV1(r, a, w1, w2, w3)                                              \
    r.x = fmaf(k0.x, a.x, fmaf(k1.x, w1.x, fmaf(k2.x, w2.x, k3.x * w3.x)));  \
    r.y = fmaf(k0.y, a.y, fmaf(k1.y, w1.y, fmaf(k2.y, w2.y, k3.y * w3.y)));  \
    r.z = fmaf(k0.z, a.z, fmaf(k1.z, w1.z, fmaf(k2.z, w2.z, k3.z * w3.z)));  \
    r.w = fmaf(k0.w, a.w, fmaf(k1.w, w1.w, fmaf(k2.w, w2.w, k3.w * w3.w)));  \
    r.x = silu_f(r.x); r.y = silu_f(r.y); r.z = silu_f(r.z); r.w = silu_f(r.w);

    float4 r0_, r1_, r2_, r3_;
    f4 r0, r1, r2, r3;
    (void)r0_; (void)r1_; (void)r2_; (void)r3_;
    CONV1(r0, a0, m1, m2, m3)
    CONV1(r1, a1, a0, m1, m2)
    CONV1(r2, a2, a1, a0, m1)
    CONV1(r3, a3, a2, a1, a0)
#undef CONV1

    f4* yp = y + (((size_t)b * T_ + t0) * C4_ + c4);
    yp[0 * C4_] = r0;
    yp[1 * C4_] = r1;
    yp[2 * C4_] = r2;
    yp[3 * C4_] = r3;

    // Fused next_cache = x[:, T-3:, :]: the last t-group (t0 = T-4) holds
    // a1 = x[T-3], a2 = x[T-2], a3 = x[T-1].
    if (tg == NT_ - 1) {
        f4* cb = cache + (size_t)b * (K_ - 1) * C4_ + c4;
        cb[0 * C4_] = a1;
        cb[1 * C4_] = a2;
        cb[2 * C4_] = a3;
    }
}

extern "C" void kernel_launch(void* const* d_in, const int* in_sizes, int n_in,
                              void* d_out, int out_size, void* d_ws, size_t ws_size,
                              hipStream_t stream)
{
    const f4* x    = (const f4*)d_in[0];
    const f4* kern = (const f4*)d_in[1];
    float*    out  = (float*)d_out;

    f4* y     = (f4*)out;
    f4* cache = (f4*)(out + (size_t)B_ * T_ * C_);

    const int total_threads = B_ * NT_ * C4_;          // 2,097,152
    dim3 grid(total_threads / 256);                    // 8192 blocks
    dim3 block(256);
    dwconv_silu_kernel<<<grid, block, 0, stream>>>(x, kern, y, cache);
}